// Round 8
// baseline (8509.054 us; speedup 1.0000x reference)
//
#include <hip/hip_runtime.h>
#include <cstdint>
#include <cstddef>

#define B_ 64
#define S_ 512
#define H_ 1024
#define E_ 128
#define L_ 49
#define G3_ 3072   // 3*H
#define K_ 1152    // E+H
#define C_ 32      // chunk length (steps), even
#define NCH_ 16    // 512 / C_

typedef short bf16x8 __attribute__((ext_vector_type(8)));
typedef float f32x4 __attribute__((ext_vector_type(4)));
typedef unsigned int u32x2 __attribute__((ext_vector_type(2)));

// bf16 round-to-nearest-even helpers (no NaN inputs here)
__device__ __forceinline__ unsigned short f2bf(float f) {
  unsigned int u = __builtin_bit_cast(unsigned int, f);
  return (unsigned short)((u + 0x7FFFu + ((u >> 16) & 1u)) >> 16);
}
__device__ __forceinline__ float bf2f(unsigned short h) {
  unsigned int u = ((unsigned int)h) << 16;
  return __builtin_bit_cast(float, u);
}

// coherent (L1/L2-bypass, L3-fresh) asm memory ops (scan h-exchange)
#define GLOAD16(dst, a64) asm volatile("global_load_dwordx4 %0, %1, off sc0 sc1" : "=v"(dst) : "v"(a64))
#define GLOAD8(dst, a64)  asm volatile("global_load_dwordx2 %0, %1, off sc0 sc1" : "=v"(dst) : "v"(a64))
#define GSTORE8(a64, v2)  asm volatile("global_store_dwordx2 %0, %1, off sc0 sc1" :: "v"(a64), "v"(v2) : "memory")
#define WAITV(N) asm volatile("s_waitcnt vmcnt(" #N ")")

// ---------------------------------------------------------------------------
// init: zero bf16 h-planes (4x128KB) + barrier state = 528384 B exact
// ---------------------------------------------------------------------------
__global__ __launch_bounds__(256) void init_kernel(float4* __restrict__ p)
{
  const int i = blockIdx.x * 256 + threadIdx.x;   // grid 129*256 = 33024 exact
  p[i] = make_float4(0.f, 0.f, 0.f, 0.f);
}

// ---------------------------------------------------------------------------
// prep_w (once): w_ih fp32 [3072][1152] -> bf16 hi/lo planes in MFMA-fragment-
// linear layout: slot idx = ((ct*36+ks)*4+kg)*128 + m  <->  row c=ct*128+m,
// k = ks*32 + kg*8 + i  (i = 0..7 within the 16B slot).
// ---------------------------------------------------------------------------
__global__ __launch_bounds__(256) void prep_w(
    const float* __restrict__ w_ih, short* __restrict__ Wh, short* __restrict__ Wl)
{
  const int idx = blockIdx.x * 256 + threadIdx.x;   // grid 1728*256 = 442368 exact
  const int m = idx & 127;
  const int slot = idx >> 7;
  const int kg = slot & 3;
  const int cks = slot >> 2;
  const int ks = cks % 36, ct = cks / 36;
  const float* src = w_ih + (size_t)(ct * 128 + m) * K_ + (ks * 32 + kg * 8);
  bf16x8 h, l;
#pragma unroll
  for (int i = 0; i < 8; ++i) {
    const float f = src[i];
    const unsigned short hh = f2bf(f);
    h[i] = (short)hh;
    l[i] = (short)f2bf(f - bf2f(hh));
  }
  *(bf16x8*)(Wh + (size_t)idx * 8) = h;
  *(bf16x8*)(Wl + (size_t)idx * 8) = l;
}

// ---------------------------------------------------------------------------
// prep_x (per chunk): assemble x[k, n] (k<128: emb[prev_id], else word) ->
// bf16 hi/lo planes, layout [(k>>3)][n][k&7]: idx = s8*2048 + n, n = tl*64+b.
// Lanes are n-consecutive -> writes perfectly coalesced.
// ---------------------------------------------------------------------------
__global__ __launch_bounds__(256) void prep_x(
    const float* __restrict__ word, const int* __restrict__ labels,
    const float* __restrict__ emb, short* __restrict__ Xh, short* __restrict__ Xl,
    int t0)
{
  const int idx = blockIdx.x * 256 + threadIdx.x;   // grid 1152*256 = 294912 exact
  const int n = idx & 2047;        // C_*64 = 2048 n's
  const int s8 = idx >> 11;        // 0..143
  const int tl = n >> 6, b = n & 63;
  const int t = t0 + tl;
  const int k0 = s8 * 8;
  const float* src;
  if (k0 < E_) {
    const int pid = (t > 0) ? labels[b * S_ + t - 1] : 0;
    src = emb + (size_t)pid * E_ + k0;
  } else {
    src = word + ((size_t)b * S_ + t) * H_ + (k0 - E_);
  }
  bf16x8 h, l;
#pragma unroll
  for (int i = 0; i < 8; ++i) {
    const float f = src[i];
    const unsigned short hh = f2bf(f);
    h[i] = (short)hh;
    l[i] = (short)f2bf(f - bf2f(hh));
  }
  *(bf16x8*)(Xh + (size_t)idx * 8) = h;
  *(bf16x8*)(Xl + (size_t)idx * 8) = l;
}

// ---------------------------------------------------------------------------
// gx_mfma v2 (per chunk): gxC[tl][c][b] = W.X + b_ih via bf16-split MFMA.
// *** NO LDS, NO global_load_lds (round-6/7 bisect): fragments are loaded
// directly global->VGPR. prep_w/prep_x layouts are fragment-linear, so each
// 16-lane group's load is a contiguous 256B segment (fully coalesced);
// W/X are L2-resident. Register double-buffer, compile-time buf indices
// (full unroll), no barriers in the K-loop. ***
// Tile 128c x 128n, BK=32, 4 waves 2x2, wave = 64x64 = 4x4 frags 16x16x32,
// 3-term split (Whi*Xhi + Whi*Xlo + Wlo*Xhi) into one acc.
// Grid: 24 ct x 16 nt = 384 blocks.
// ---------------------------------------------------------------------------
__global__ __launch_bounds__(256, 2) void gx_mfma(
    const short* __restrict__ Wh, const short* __restrict__ Wl,
    const short* __restrict__ Xh, const short* __restrict__ Xl,
    const float* __restrict__ b_ih, float* __restrict__ gxC)
{
  const int tid = threadIdx.x;
  const int nt = blockIdx.x & 15, ct = blockIdx.x >> 4;
  const int lane = tid & 63, w = tid >> 6;
  const int wm = w & 1, wn = w >> 1;
  const int lo16 = lane & 15, hi4 = lane >> 4;

  // per-lane element offsets (shorts):
  //   A(ks,f) = abase + ks*4096 + f*128   (slot = (ct*36+ks)*4+hi4, row wm*64+f*16+lo16)
  //   B(ks,f) = bbase + ks*65536 + f*128  (s8 = ks*4+hi4, n = nt*128+wn*64+f*16+lo16)
  const size_t abase = ((size_t)(ct * 36) * 512 + (size_t)hi4 * 128 + wm * 64 + lo16) * 8;
  const size_t bbase = ((size_t)hi4 * 2048 + nt * 128 + wn * 64 + lo16) * 8;

  bf16x8 ah[2][4], al[2][4], xh[2][4], xl[2][4];
  f32x4 acc[4][4];
#pragma unroll
  for (int a = 0; a < 4; ++a)
#pragma unroll
    for (int bq = 0; bq < 4; ++bq) acc[a][bq] = (f32x4){0.f, 0.f, 0.f, 0.f};

#pragma unroll
  for (int f = 0; f < 4; ++f) {
    ah[0][f] = *(const bf16x8*)(Wh + abase + (size_t)f * 128);
    al[0][f] = *(const bf16x8*)(Wl + abase + (size_t)f * 128);
    xh[0][f] = *(const bf16x8*)(Xh + bbase + (size_t)f * 128);
    xl[0][f] = *(const bf16x8*)(Xl + bbase + (size_t)f * 128);
  }

#pragma unroll
  for (int ks = 0; ks < 36; ++ks) {
    const int cur = ks & 1;         // compile-time (full unroll)
    if (ks < 35) {
      const size_t a1 = abase + (size_t)(ks + 1) * 4096;
      const size_t b1 = bbase + (size_t)(ks + 1) * 65536;
#pragma unroll
      for (int f = 0; f < 4; ++f) {
        ah[cur ^ 1][f] = *(const bf16x8*)(Wh + a1 + (size_t)f * 128);
        al[cur ^ 1][f] = *(const bf16x8*)(Wl + a1 + (size_t)f * 128);
        xh[cur ^ 1][f] = *(const bf16x8*)(Xh + b1 + (size_t)f * 128);
        xl[cur ^ 1][f] = *(const bf16x8*)(Xl + b1 + (size_t)f * 128);
      }
    }
#pragma unroll
    for (int mf = 0; mf < 4; ++mf)
#pragma unroll
      for (int nf = 0; nf < 4; ++nf) {
        acc[mf][nf] = __builtin_amdgcn_mfma_f32_16x16x32_bf16(ah[cur][mf], xh[cur][nf], acc[mf][nf], 0, 0, 0);
        acc[mf][nf] = __builtin_amdgcn_mfma_f32_16x16x32_bf16(ah[cur][mf], xl[cur][nf], acc[mf][nf], 0, 0, 0);
        acc[mf][nf] = __builtin_amdgcn_mfma_f32_16x16x32_bf16(al[cur][mf], xh[cur][nf], acc[mf][nf], 0, 0, 0);
      }
  }

  // epilogue: bias + store. D frag: col = lo16, row = hi4*4 + r.
  const int tl = nt * 2 + wn;
  float* outb = gxC + (size_t)tl * (G3_ * 64);
#pragma unroll
  for (int mf = 0; mf < 4; ++mf) {
    const int c0 = ct * 128 + wm * 64 + mf * 16 + hi4 * 4;
#pragma unroll
    for (int r = 0; r < 4; ++r) {
      const float bv = b_ih[c0 + r];
#pragma unroll
      for (int nf = 0; nf < 4; ++nf)
        outb[(size_t)(c0 + r) * 64 + nf * 16 + lo16] = acc[mf][nf][r] + bv;
    }
  }
}

// ---------------------------------------------------------------------------
// Phase 2 (per chunk): MFMA GRU scan (round-5-validated; C_ steps).
// ---------------------------------------------------------------------------
__global__ __launch_bounds__(256, 1) void scan_kernel(
    const float* __restrict__ gxC, const float* __restrict__ w_hh,
    const float* __restrict__ b_hh,
    char* phiA, char* ploA, char* phiB, char* ploB,
    float* __restrict__ outsC, unsigned* bar, unsigned step0)
{
  const int g = blockIdx.x;
  const int tid = threadIdx.x;
  const int lane = tid & 63;
  const int w = tid >> 6;          // wave id = n-tile index
  const int m = lane & 15;         // A row / D col position
  const int gA = lane >> 4;        // k-group
  const int bl = m;                // gate lane's batch-low (lanes 0-15)

  // ---- A-fragments: rows gate*1024 + 4g + (m&3); zeros for pad rows m>=12
  bf16x8 whi[32], wlo[32];
  {
    const bool valid = (m < 12);
    const int msafe = valid ? m : 0;
    const float* wr = w_hh + (size_t)((msafe >> 2) * 1024 + 4 * g + (msafe & 3)) * 1024;
#pragma unroll
    for (int ks = 0; ks < 32; ++ks) {
      const int kb = ks * 32 + gA * 8;
      float v[8];
      const float4 a0 = *(const float4*)(wr + kb);
      const float4 a1 = *(const float4*)(wr + kb + 4);
      v[0] = a0.x; v[1] = a0.y; v[2] = a0.z; v[3] = a0.w;
      v[4] = a1.x; v[5] = a1.y; v[6] = a1.z; v[7] = a1.w;
#pragma unroll
      for (int i = 0; i < 8; ++i) {
        const float f = valid ? v[i] : 0.f;
        const unsigned short hh = f2bf(f);
        const unsigned short hl = f2bf(f - bf2f(hh));
        whi[ks][i] = (short)hh;
        wlo[ks][i] = (short)hl;
      }
    }
  }

  // ---- gate constants + plane address for this lane's (4 jj, b) slot
  const int ksj = g >> 3;
  const int gf  = (g >> 1) & 3;
  const unsigned gbyte =
      ((unsigned)((ksj * 4 + w) * 64 + gf * 16 + bl)) * 16u + 8u * (g & 1);
  float bh_r[4], bh_z[4], bh_n[4], hold[4];
#pragma unroll
  for (int jj = 0; jj < 4; ++jj) {
    bh_r[jj] = b_hh[4 * g + jj];
    bh_z[jj] = b_hh[1024 + 4 * g + jj];
    bh_n[jj] = b_hh[2048 + 4 * g + jj];
  }
  {
    u32x2 dh, dl;
    GLOAD8(dh, (uint64_t)(uintptr_t)(phiA + gbyte));
    GLOAD8(dl, (uint64_t)(uintptr_t)(ploA + gbyte));
    WAITV(0);
    __builtin_amdgcn_sched_barrier(0);
#pragma unroll
    for (int jj = 0; jj < 4; ++jj) {
      const unsigned short hh = (unsigned short)((dh[jj >> 1] >> ((jj & 1) * 16)) & 0xFFFFu);
      const unsigned short hl = (unsigned short)((dl[jj >> 1] >> ((jj & 1) * 16)) & 0xFFFFu);
      hold[jj] = bf2f(hh) + bf2f(hl);
    }
  }

  char* curHi = phiA; char* curLo = ploA;
  char* nxtHi = phiB; char* nxtLo = ploB;

  for (int s = 0; s < C_; ++s) {
    // ---- gate inputs for this step (plain loads; lanes>=16 replicate bl)
    float gr[4], gz[4], gn[4];
    {
      const float* gp = gxC + (size_t)s * (G3_ * 64) + 16 * w + bl;
#pragma unroll
      for (int jj = 0; jj < 4; ++jj) {
        gr[jj] = gp[(0 * 1024 + 4 * g + jj) * 64];
        gz[jj] = gp[(1 * 1024 + 4 * g + jj) * 64];
        gn[jj] = gp[(2 * 1024 + 4 * g + jj) * 64];
      }
    }

    // ---- MFMA over K: B-frags streamed via asm sc1 loads, 2-group pipeline
    const uint64_t bHi = (uint64_t)(uintptr_t)curHi + (unsigned)((w << 10) + (lane << 4));
    const uint64_t bLo = (uint64_t)(uintptr_t)curLo + (unsigned)((w << 10) + (lane << 4));
    bf16x8 bh[2][4], blo[2][4];
    f32x4 acc[6];
#pragma unroll
    for (int c = 0; c < 6; ++c) acc[c] = (f32x4){0.f, 0.f, 0.f, 0.f};

#pragma unroll
    for (int q = 0; q < 4; ++q) {
      GLOAD16(bh[0][q],  bHi + (unsigned)((0 * 4 + q) * 4096));
      GLOAD16(blo[0][q], bLo + (unsigned)((0 * 4 + q) * 4096));
    }
#pragma unroll
    for (int q = 0; q < 4; ++q) {
      GLOAD16(bh[1][q],  bHi + (unsigned)((1 * 4 + q) * 4096));
      GLOAD16(blo[1][q], bLo + (unsigned)((1 * 4 + q) * 4096));
    }

#pragma unroll
    for (int grp = 0; grp < 8; ++grp) {
      if (grp < 7) { WAITV(8); } else { WAITV(0); }
      __builtin_amdgcn_sched_barrier(0);
      const int buf = grp & 1;
#pragma unroll
      for (int q = 0; q < 4; ++q) {
        const int ks = grp * 4 + q;
        const int p = (ks & 1) * 3;
        acc[p + 0] = __builtin_amdgcn_mfma_f32_16x16x32_bf16(whi[ks], bh[buf][q],  acc[p + 0], 0, 0, 0);
        acc[p + 1] = __builtin_amdgcn_mfma_f32_16x16x32_bf16(whi[ks], blo[buf][q], acc[p + 1], 0, 0, 0);
        acc[p + 2] = __builtin_amdgcn_mfma_f32_16x16x32_bf16(wlo[ks], bh[buf][q],  acc[p + 2], 0, 0, 0);
      }
      if (grp + 2 < 8) {
#pragma unroll
        for (int q = 0; q < 4; ++q) {
          GLOAD16(bh[buf][q],  bHi + (unsigned)(((grp + 2) * 4 + q) * 4096));
          GLOAD16(blo[buf][q], bLo + (unsigned)(((grp + 2) * 4 + q) * 4096));
        }
      }
    }

    f32x4 P = (acc[0] + acc[3]) + (acc[1] + acc[4]) + (acc[2] + acc[5]);

    // ---- gather z/n partials to lanes 0-15
    float zs[4], ns[4];
#pragma unroll
    for (int jj = 0; jj < 4; ++jj) {
      zs[jj] = __shfl(P[jj], bl + 16);
      ns[jj] = __shfl(P[jj], bl + 32);
    }

    if (lane < 16) {
      const int b = 16 * w + bl;
      unsigned short hhi[4], hlo[4];
#pragma unroll
      for (int jj = 0; jj < 4; ++jj) {
        const float r = 1.f / (1.f + expf(-(gr[jj] + P[jj] + bh_r[jj])));
        const float z = 1.f / (1.f + expf(-(gz[jj] + zs[jj] + bh_z[jj])));
        const float n = tanhf(gn[jj] + r * (ns[jj] + bh_n[jj]));
        const float hnew = (1.f - z) * n + z * hold[jj];
        hold[jj] = hnew;
        outsC[((size_t)s << 16) + (size_t)((4 * g + jj) << 6) + b] = hnew;
        hhi[jj] = f2bf(hnew);
        hlo[jj] = f2bf(hnew - bf2f(hhi[jj]));
      }
      u32x2 vh, vl;
      vh[0] = (unsigned)hhi[0] | ((unsigned)hhi[1] << 16);
      vh[1] = (unsigned)hhi[2] | ((unsigned)hhi[3] << 16);
      vl[0] = (unsigned)hlo[0] | ((unsigned)hlo[1] << 16);
      vl[1] = (unsigned)hlo[2] | ((unsigned)hlo[3] << 16);
      GSTORE8((uint64_t)(uintptr_t)(nxtHi + gbyte), vh);
      GSTORE8((uint64_t)(uintptr_t)(nxtLo + gbyte), vl);
    }

    // ---- relaxed grid barrier
    __syncthreads();
    if (tid == 0) {
      asm volatile("s_waitcnt vmcnt(0)" ::: "memory");
      const unsigned tgt = step0 + (unsigned)s + 1u;
      const unsigned old =
          __hip_atomic_fetch_add(bar, 1u, __ATOMIC_RELAXED, __HIP_MEMORY_SCOPE_AGENT);
      if (old == 255u) {
        __hip_atomic_store(bar, 0u, __ATOMIC_RELAXED, __HIP_MEMORY_SCOPE_AGENT);
        asm volatile("s_waitcnt vmcnt(0)" ::: "memory");
        __hip_atomic_store(bar + 544, tgt, __ATOMIC_RELAXED, __HIP_MEMORY_SCOPE_AGENT);
      } else {
        while (__hip_atomic_load(bar + 544, __ATOMIC_RELAXED, __HIP_MEMORY_SCOPE_AGENT) < tgt)
          __builtin_amdgcn_s_sleep(1);
      }
    }
    __syncthreads();

    char* t1 = curHi; curHi = nxtHi; nxtHi = t1;
    char* t2 = curLo; curLo = nxtLo; nxtLo = t2;
  }
}

// ---------------------------------------------------------------------------
// Phase 3 (per chunk): logits + IOBES mask (unchanged)
// ---------------------------------------------------------------------------
__global__ __launch_bounds__(256) void logits_kernel(
    const float* __restrict__ outsC, const int* __restrict__ labels,
    const float* __restrict__ w_out, const float* __restrict__ b_out,
    float* __restrict__ out, int t0)
{
  __shared__ float hs[128 * 64];
  __shared__ float wso[49 * 128];
  const int tl = blockIdx.x;
  const int t  = t0 + tl;
  const int tid = threadIdx.x;
  const int b = tid & 63, lq = tid >> 6;
  const int l0 = lq * 13;
  const int nl = (lq == 3) ? 10 : 13;

  float acc[13];
#pragma unroll
  for (int i = 0; i < 13; ++i) acc[i] = 0.f;

  for (int kc = 0; kc < 8; ++kc) {
    __syncthreads();
#pragma unroll
    for (int i = 0; i < 8; ++i) {
      const int flat = (i << 10) + (tid << 2);
      *(float4*)&hs[flat] = *(const float4*)&outsC[((size_t)tl << 16) + (kc << 13) + flat];
    }
    for (int idx = tid; idx < 1568; idx += 256) {
      const int l = idx >> 5, k4 = idx & 31;
      *(float4*)&wso[l * 128 + (k4 << 2)] =
          *(const float4*)&w_out[(size_t)l * 1024 + (kc << 7) + (k4 << 2)];
    }
    __syncthreads();
    for (int k = 0; k < 128; k += 4) {
      const float h0 = hs[((k + 0) << 6) + b];
      const float h1 = hs[((k + 1) << 6) + b];
      const float h2 = hs[((k + 2) << 6) + b];
      const float h3 = hs[((k + 3) << 6) + b];
#pragma unroll
      for (int li = 0; li < 13; ++li) {
        if (li < nl) {
          const float4 wv = *(const float4*)&wso[(l0 + li) * 128 + k];
          acc[li] = fmaf(wv.w, h3, fmaf(wv.z, h2, fmaf(wv.y, h1, fmaf(wv.x, h0, acc[li]))));
        }
      }
    }
  }

  const int pid = (t > 0) ? labels[b * S_ + t - 1] : 0;
  bool prevOES;
  int ptype = 0;
  if (pid == 0) { prevOES = true; }
  else {
    const int pp = (pid - 1) & 3;   // 0:B 1:I 2:E 3:S
    prevOES = (pp >= 2);
    ptype = (pid - 1) >> 2;
  }
#pragma unroll
  for (int li = 0; li < 13; ++li) {
    if (li < nl) {
      const int l = l0 + li;
      bool ok;
      if (prevOES) {
        ok = (l == 0) || (((l - 1) & 3) == 0) || (((l - 1) & 3) == 3);
      } else {
        ok = (l > 0) && (((l - 1) >> 2) == ptype) &&
             ((((l - 1) & 3) == 1) || (((l - 1) & 3) == 2));
      }
      out[(((size_t)b << 9) + t) * 49 + l] = ok ? (acc[li] + b_out[l]) : -1e12f;
    }
  }
}

// ---------------------------------------------------------------------------
// ws layout (total 49,287,168 B ~ 49.3 MB -- under the 67.6 MB proven bound):
//   gxC   @ 0          : 25,165,824   [C_=32][3072][64] f32
//   Xh    @ 25,165,824 :  4,718,592   bf16 frag layout  } aliased with
//   Xl    @ 29,884,416 :  4,718,592   bf16 frag layout  } outsC (8.4 MB):
//   outsC @ 25,165,824 :  8,388,608   X dead before scan writes outsC
//   phiA  @ 34,603,008 :    131,072   bf16 h-plane hi, set A
//   ploA  @ 34,734,080 :    131,072
//   phiB  @ 34,865,152 :    131,072
//   ploB  @ 34,996,224 :    131,072
//   bar   @ 35,127,296 :      4,096   (cnt @ +0, gen @ +544 dwords)
//   Wh    @ 35,131,392 :  7,077,888   bf16 frag layout (prep_w, once)
//   Wl    @ 42,209,280 :  7,077,888
// ---------------------------------------------------------------------------
extern "C" void kernel_launch(void* const* d_in, const int* in_sizes, int n_in,
                              void* d_out, int out_size, void* d_ws, size_t ws_size,
                              hipStream_t stream)
{
  const float* word   = (const float*)d_in[0];
  const int*   labels = (const int*)d_in[1];
  const float* emb    = (const float*)d_in[2];
  const float* w_ih   = (const float*)d_in[3];
  const float* w_hh   = (const float*)d_in[4];
  const float* b_ih   = (const float*)d_in[5];
  const float* b_hh   = (const float*)d_in[6];
  const float* w_out  = (const float*)d_in[7];
  const float* b_out  = (const float*)d_in[8];
  float* out = (float*)d_out;

  if (ws_size < 49287168ull) return;   // fail clean, never scribble

  char* ws = (char*)d_ws;
  float*    gxC   = (float*)ws;
  short*    Xh    = (short*)(ws + 25165824ull);
  short*    Xl    = (short*)(ws + 29884416ull);
  float*    outsC = (float*)(ws + 25165824ull);   // alias over Xh/Xl (see map)
  char*     phiA  = ws + 34603008ull;
  char*     ploA  = ws + 34734080ull;
  char*     phiB  = ws + 34865152ull;
  char*     ploB  = ws + 34996224ull;
  unsigned* bar   = (unsigned*)(ws + 35127296ull);
  short*    Wh    = (short*)(ws + 35131392ull);
  short*    Wl    = (short*)(ws + 42209280ull);

  init_kernel<<<dim3(129), dim3(256), 0, stream>>>((float4*)phiA);  // planes+bar=0
  prep_w<<<dim3(1728), dim3(256), 0, stream>>>(w_ih, Wh, Wl);

  for (int ch = 0; ch < NCH_; ++ch) {
    const int t0 = ch * C_;
    prep_x<<<dim3(1152), dim3(256), 0, stream>>>(word, labels, emb, Xh, Xl, t0);
    gx_mfma<<<dim3(384), dim3(256), 0, stream>>>(Wh, Wl, Xh, Xl, b_ih, gxC);
    scan_kernel<<<dim3(256), dim3(256), 0, stream>>>(gxC, w_hh, b_hh,
                                                     phiA, ploA, phiB, ploB,
                                                     outsC, bar, (unsigned)t0);
    logits_kernel<<<dim3(C_), dim3(256), 0, stream>>>(outsC, labels, w_out, b_out,
                                                      out, t0);
  }
}